// Round 1
// baseline (5173.029 us; speedup 1.0000x reference)
//
#include <hip/hip_runtime.h>
#include <cstdint>
#include <cstddef>

#define BB 8
#define NN 8192
#define SS 2048
#define KNB 32

// Bit-exact squared distance matching numpy: (a-b) per component, squares,
// left-to-right sum, no FMA contraction.
__device__ __forceinline__ float sqdist_exact(float ax, float ay, float az,
                                              float bx, float by, float bz) {
#pragma clang fp contract(off)
    float dx = ax - bx;
    float dy = ay - by;
    float dz = az - bz;
    return (dx * dx + dy * dy) + dz * dz;
}

// ---------------------------------------------------------------------------
// Weight transpose prep: w1T[c][64], w2T[j][64], w3T[j][128]
// ---------------------------------------------------------------------------
__global__ void prep_kernel(const float* __restrict__ w1, const float* __restrict__ w2,
                            const float* __restrict__ w3, float* __restrict__ w1T,
                            float* __restrict__ w2T, float* __restrict__ w3T) {
    for (int i = threadIdx.x; i < 192; i += 256) {
        int oc = i / 3, c = i % 3;
        w1T[c * 64 + oc] = w1[i];
    }
    for (int i = threadIdx.x; i < 4096; i += 256) {
        int oc = i >> 6, j = i & 63;
        w2T[j * 64 + oc] = w2[i];
    }
    for (int i = threadIdx.x; i < 8192; i += 256) {
        int oc = i >> 6, j = i & 63;
        w3T[j * 128 + oc] = w3[i];
    }
}

// ---------------------------------------------------------------------------
// FPS: one block per batch. Prologue: 8x8x8 cell counting sort (spatial
// grouping) staged through global ws. Each of 512 threads owns 16 sorted
// points in registers + a bbox. Main loop: thread-level bbox pruning (exact:
// skip only when provably no dist can change, 1e-3 margin covers rounding),
// block argmax reduction with (value, min-orig-index) tie-break == jnp.argmax.
// ---------------------------------------------------------------------------
__global__ __launch_bounds__(512) void fps_kernel(const float* __restrict__ xyz_all,
                                                  float4* __restrict__ wsSorted,
                                                  float4* __restrict__ wsCtr,
                                                  float* __restrict__ out0) {
    const int b = blockIdx.x;
    const float* xyz = xyz_all + (size_t)b * NN * 3;
    float4* sorted = wsSorted + (size_t)b * NN;
    float4* ctr = wsCtr + (size_t)b * SS;
    float* o0 = out0 + (size_t)b * 3 * SS;

    __shared__ int cellCnt[512];
    __shared__ int cellBase[512];
    __shared__ float redV[8];
    __shared__ int redI[8];
    __shared__ float bcast[3];

    const int tid = threadIdx.x;

    // --- pass 1: per-cell counts
    cellCnt[tid] = 0;
    __syncthreads();
    for (int j = 0; j < 16; ++j) {
        int p = tid + j * 512;
        float x = xyz[p * 3 + 0], y = xyz[p * 3 + 1], z = xyz[p * 3 + 2];
        int cx = min(7, (int)(x * 8.0f));
        int cy = min(7, (int)(y * 8.0f));
        int cz = min(7, (int)(z * 8.0f));
        int cell = (cz * 8 + cy) * 8 + cx;
        atomicAdd(&cellCnt[cell], 1);
    }
    __syncthreads();
    int myCnt = cellCnt[tid];
    // inclusive Hillis-Steele scan over 512 cells (thread==cell)
    for (int off = 1; off < 512; off <<= 1) {
        int v = (tid >= off) ? cellCnt[tid - off] : 0;
        __syncthreads();
        cellCnt[tid] += v;
        __syncthreads();
    }
    cellBase[tid] = cellCnt[tid] - myCnt;
    __syncthreads();
    // --- pass 2: scatter (x,y,z,origIdx) into sorted order via global ws
    for (int j = 0; j < 16; ++j) {
        int p = tid + j * 512;
        float x = xyz[p * 3 + 0], y = xyz[p * 3 + 1], z = xyz[p * 3 + 2];
        int cx = min(7, (int)(x * 8.0f));
        int cy = min(7, (int)(y * 8.0f));
        int cz = min(7, (int)(z * 8.0f));
        int cell = (cz * 8 + cy) * 8 + cx;
        int pos = atomicAdd(&cellBase[cell], 1);
        sorted[pos] = make_float4(x, y, z, __int_as_float(p));
    }
    __threadfence_block();
    __syncthreads();

    // --- load own 16 points into registers, build bbox
    float px[16], py[16], pz[16], dist[16];
    int od[16];
    float lox = 1e30f, loy = 1e30f, loz = 1e30f;
    float hix = -1e30f, hiy = -1e30f, hiz = -1e30f;
    int bi = 0x7fffffff;
#pragma unroll
    for (int j = 0; j < 16; ++j) {
        float4 v = sorted[tid * 16 + j];
        px[j] = v.x; py[j] = v.y; pz[j] = v.z;
        od[j] = __float_as_int(v.w);
        dist[j] = 1e10f;
        lox = fminf(lox, v.x); hix = fmaxf(hix, v.x);
        loy = fminf(loy, v.y); hiy = fmaxf(hiy, v.y);
        loz = fminf(loz, v.z); hiz = fmaxf(hiz, v.z);
        bi = min(bi, od[j]);
    }
    float bv = 1e10f;  // (bv,bi) = this thread's current argmax candidate

    float cx = xyz[0], cy = xyz[1], cz = xyz[2];
    int f = 0;

    for (int s = 0; s < SS; ++s) {
        if (tid == 0) {
            ctr[s] = make_float4(cx, cy, cz, __int_as_float(f));
            o0[s] = cx;
            o0[SS + s] = cy;
            o0[2 * SS + s] = cz;
        }
        if (s == SS - 1) break;

        // bbox lower-bound prune (margin-safe; only loosens pruning)
        float ddx = fmaxf(fmaxf(lox - cx, cx - hix), 0.0f);
        float ddy = fmaxf(fmaxf(loy - cy, cy - hiy), 0.0f);
        float ddz = fmaxf(fmaxf(loz - cz, cz - hiz), 0.0f);
        float lb2 = ddx * ddx + ddy * ddy + ddz * ddz;
        if (lb2 * 0.999f < bv) {
            float nbv = -1.0f;
            int nbi = 0x7fffffff;
#pragma unroll
            for (int j = 0; j < 16; ++j) {
                float d = sqdist_exact(px[j], py[j], pz[j], cx, cy, cz);
                float nd = fminf(dist[j], d);
                dist[j] = nd;
                bool better = (nd > nbv) || (nd == nbv && od[j] < nbi);
                nbv = better ? nd : nbv;
                nbi = better ? od[j] : nbi;
            }
            bv = nbv;
            bi = nbi;
        }

        // block argmax reduction, first-index tie-break
        float rv = bv;
        int ri = bi;
#pragma unroll
        for (int off = 32; off > 0; off >>= 1) {
            float ov = __shfl_down(rv, off);
            int oi = __shfl_down(ri, off);
            bool better = (ov > rv) || (ov == rv && oi < ri);
            rv = better ? ov : rv;
            ri = better ? oi : ri;
        }
        if ((tid & 63) == 0) {
            redV[tid >> 6] = rv;
            redI[tid >> 6] = ri;
        }
        __syncthreads();
        float wv = redV[0];
        int wi = redI[0];
#pragma unroll
        for (int k = 1; k < 8; ++k) {
            float ov = redV[k];
            int oi = redI[k];
            bool better = (ov > wv) || (ov == wv && oi < wi);
            wv = better ? ov : wv;
            wi = better ? oi : wi;
        }
        // unique owner of wi publishes its coordinates
        if (bi == wi) {
            float x = px[0], y = py[0], z = pz[0];
#pragma unroll
            for (int j = 1; j < 16; ++j) {
                bool m = (od[j] == wi);
                x = m ? px[j] : x;
                y = m ? py[j] : y;
                z = m ? pz[j] : z;
            }
            bcast[0] = x; bcast[1] = y; bcast[2] = z;
        }
        __syncthreads();
        cx = bcast[0]; cy = bcast[1]; cz = bcast[2];
        f = wi;
    }
}

// ---------------------------------------------------------------------------
// Fused ball-query + MLP + maxpool. Block = 128 threads (2 waves), 2 centers.
// Wave w ball-queries center s0+w: ascending-index scan in 64-point chunks
// with ballot compaction; first 32 in-radius indices == jnp.sort semantics;
// pad with first member's rel. Then 3 GEMM-ish layers with activations in
// LDS (h1T/h2T: [ch][row]) and wave-uniform weight rows (s_load + SGPR FMA).
// Maxpool over the 32 rows of a center = shfl_xor butterfly in 32-lane halves.
// ---------------------------------------------------------------------------
__global__ __launch_bounds__(128) void bqmlp_kernel(const float* __restrict__ xyz_all,
                                                    const float4* __restrict__ wsCtr,
                                                    const float* __restrict__ w1T,
                                                    const float* __restrict__ b1,
                                                    const float* __restrict__ w2T,
                                                    const float* __restrict__ b2,
                                                    const float* __restrict__ w3T,
                                                    const float* __restrict__ b3,
                                                    float* __restrict__ out1) {
    const int b = blockIdx.x >> 10;            // 1024 blocks per batch
    const int s0 = (blockIdx.x & 1023) * 2;    // 2 centers per block
    const float* xyz = xyz_all + (size_t)b * NN * 3;

    __shared__ float relF[2 * KNB * 3];  // [64 rows][3]
    __shared__ float h1T[64 * 64];       // [ch][row]
    __shared__ float h2T[64 * 64];       // [ch][row]

    const int tid = threadIdx.x;
    const int cb = __builtin_amdgcn_readfirstlane(tid >> 6);  // wave id (uniform)
    const int l = tid & 63;

    // ---- ball query: wave cb handles center s0+cb
    {
        float4 cc = wsCtr[(size_t)b * SS + s0 + cb];
        float ccx = cc.x, ccy = cc.y, ccz = cc.z;
        const float R2 = (float)(0.2 * 0.2);
        int total = 0;
        float fx = 0.f, fy = 0.f, fz = 0.f;
        bool have = false;
        for (int chunk = 0; chunk < 128 && total < KNB; ++chunk) {
            int p = chunk * 64 + l;
            float x = xyz[p * 3 + 0], y = xyz[p * 3 + 1], z = xyz[p * 3 + 2];
            float d = sqdist_exact(ccx, ccy, ccz, x, y, z);
            bool hit = (d <= R2);
            unsigned long long mask = __ballot(hit);
            int cnt = __popcll(mask);
            if (cnt) {
                int pos = total + __popcll(mask & ((1ull << l) - 1ull));
                float rx = x - ccx, ry = y - ccy, rz = z - ccz;  // single subs: exact
                if (hit && pos < KNB) {
                    relF[(cb * KNB + pos) * 3 + 0] = rx;
                    relF[(cb * KNB + pos) * 3 + 1] = ry;
                    relF[(cb * KNB + pos) * 3 + 2] = rz;
                }
                if (hit && pos == 0) { fx = rx; fy = ry; fz = rz; have = true; }
                total += cnt;
            }
        }
        unsigned long long hm = __ballot(have);
        if (total < KNB) {
            int src = __ffsll((long long)hm) - 1;
            float gx = __shfl(fx, src), gy = __shfl(fy, src), gz = __shfl(fz, src);
            if (l >= total && l < KNB) {
                relF[(cb * KNB + l) * 3 + 0] = gx;
                relF[(cb * KNB + l) * 3 + 1] = gy;
                relF[(cb * KNB + l) * 3 + 2] = gz;
            }
        }
    }
    __syncthreads();

    const int r = l;  // row 0..63 (= center cb? no: rows 0..31 center s0, 32..63 center s0+1)

    // ---- layer 1: rel(3) -> 64, thread covers ch block cb*32..+31 for row r
    {
        float rx = relF[r * 3 + 0], ry = relF[r * 3 + 1], rz = relF[r * 3 + 2];
#pragma unroll
        for (int i = 0; i < 32; ++i) {
            int ch = cb * 32 + i;
            float h = b1[ch];
            h = fmaf(rx, w1T[0 * 64 + ch], h);
            h = fmaf(ry, w1T[1 * 64 + ch], h);
            h = fmaf(rz, w1T[2 * 64 + ch], h);
            h1T[ch * 64 + r] = fmaxf(h, 0.0f);
        }
    }
    __syncthreads();

    // ---- layer 2: 64 -> 64
    {
        float acc[32];
#pragma unroll
        for (int i = 0; i < 32; ++i) acc[i] = b2[cb * 32 + i];
#pragma unroll 4
        for (int j = 0; j < 64; ++j) {
            float a = h1T[j * 64 + r];
            const float* wrow = w2T + j * 64 + cb * 32;
#pragma unroll
            for (int i = 0; i < 32; ++i) acc[i] = fmaf(a, wrow[i], acc[i]);
        }
#pragma unroll
        for (int i = 0; i < 32; ++i) h2T[(cb * 32 + i) * 64 + r] = fmaxf(acc[i], 0.0f);
    }
    __syncthreads();

    // ---- layer 3: 64 -> 128, fused relu + maxpool over the 32 rows/center
    {
        float acc[64];
#pragma unroll
        for (int i = 0; i < 64; ++i) acc[i] = b3[cb * 64 + i];
#pragma unroll 2
        for (int j = 0; j < 64; ++j) {
            float a = h2T[j * 64 + r];
            const float* wrow = w3T + j * 128 + cb * 64;
#pragma unroll
            for (int i = 0; i < 64; ++i) acc[i] = fmaf(a, wrow[i], acc[i]);
        }
#pragma unroll
        for (int i = 0; i < 64; ++i) {
            float v = fmaxf(acc[i], 0.0f);
            v = fmaxf(v, __shfl_xor(v, 1));
            v = fmaxf(v, __shfl_xor(v, 2));
            v = fmaxf(v, __shfl_xor(v, 4));
            v = fmaxf(v, __shfl_xor(v, 8));
            v = fmaxf(v, __shfl_xor(v, 16));
            acc[i] = v;
        }
        if ((l & 31) == 0) {
            int sA = s0 + (l >> 5);
            float* op = out1 + ((size_t)b * 128 + cb * 64) * SS + sA;
#pragma unroll
            for (int i = 0; i < 64; ++i) op[(size_t)i * SS] = acc[i];
        }
    }
}

extern "C" void kernel_launch(void* const* d_in, const int* in_sizes, int n_in,
                              void* d_out, int out_size, void* d_ws, size_t ws_size,
                              hipStream_t stream) {
    (void)in_sizes; (void)n_in; (void)out_size; (void)ws_size;
    const float* xyz = (const float*)d_in[0];
    // d_in[1] = features : unused by the reference
    const float* w1 = (const float*)d_in[2];
    const float* b1 = (const float*)d_in[3];
    const float* w2 = (const float*)d_in[4];
    const float* b2 = (const float*)d_in[5];
    const float* w3 = (const float*)d_in[6];
    const float* b3 = (const float*)d_in[7];
    float* out = (float*)d_out;

    // workspace layout
    float4* wsCtr = (float4*)d_ws;              // B*S float4      (256 KB)
    float4* wsSorted = wsCtr + BB * SS;         // B*N float4      (1 MB)
    float* w1T = (float*)(wsSorted + BB * NN);  // 192 f
    float* w2T = w1T + 192;                     // 4096 f
    float* w3T = w2T + 4096;                    // 8192 f

    prep_kernel<<<1, 256, 0, stream>>>(w1, w2, w3, w1T, w2T, w3T);
    fps_kernel<<<BB, 512, 0, stream>>>(xyz, wsSorted, wsCtr, out);
    bqmlp_kernel<<<BB * (SS / 2), 128, 0, stream>>>(xyz, wsCtr, w1T, b1, w2T, b2,
                                                    w3T, b3, out + BB * 3 * SS);
}

// Round 2
// 3963.478 us; speedup vs baseline: 1.3052x; 1.3052x over previous
//
#include <hip/hip_runtime.h>
#include <cstdint>
#include <cstddef>

#define BB 8
#define NN 8192
#define SS 2048
#define KNB 32

// Bit-exact squared distance matching numpy: (a-b) per component, squares,
// left-to-right sum, no FMA contraction.
__device__ __forceinline__ float sqdist_exact(float ax, float ay, float az,
                                              float bx, float by, float bz) {
#pragma clang fp contract(off)
    float dx = ax - bx;
    float dy = ay - by;
    float dz = az - bz;
    return (dx * dx + dy * dy) + dz * dz;
}

// ---------------------------------------------------------------------------
// Weight transpose prep: w1T[c][64], w2T[j][64], w3T[j][128]
// ---------------------------------------------------------------------------
__global__ void prep_kernel(const float* __restrict__ w1, const float* __restrict__ w2,
                            const float* __restrict__ w3, float* __restrict__ w1T,
                            float* __restrict__ w2T, float* __restrict__ w3T) {
    for (int i = threadIdx.x; i < 192; i += 256) {
        int oc = i / 3, c = i % 3;
        w1T[c * 64 + oc] = w1[i];
    }
    for (int i = threadIdx.x; i < 4096; i += 256) {
        int oc = i >> 6, j = i & 63;
        w2T[j * 64 + oc] = w2[i];
    }
    for (int i = threadIdx.x; i < 8192; i += 256) {
        int oc = i >> 6, j = i & 63;
        w3T[j * 128 + oc] = w3[i];
    }
}

// spread 3-bit value to bit positions 0,3,6
__device__ __forceinline__ int part3(int v) {
    return (v & 1) | ((v & 2) << 2) | ((v & 4) << 4);
}

// ---------------------------------------------------------------------------
// FPS: one block per batch, 512 threads (8 waves), 16 points/thread IN
// REGISTERS (launch_bounds(512,2) -> 256 VGPR budget, no spill). Points are
// counting-sorted by 8x8x8 MORTON cell so each wave owns ~one octant ->
// wave-uniform exact bbox prune (skip only when provably no dist changes;
// 0.999 margin covers fp rounding). Argmax candidate packed as u64
// (dist_bits<<32 | ~origIdx) == (max val, then min index) == jnp.argmax
// tie-break. One barrier/iter via parity double-buffered LDS slots; winner
// coords fetched as a broadcast global load from xyz.
// ---------------------------------------------------------------------------
__global__ __launch_bounds__(512, 2) void fps_kernel(const float* __restrict__ xyz_all,
                                                     float4* __restrict__ wsSorted,
                                                     float4* __restrict__ wsCtr,
                                                     float* __restrict__ out0) {
    const int b = blockIdx.x;
    const float* xyz = xyz_all + (size_t)b * NN * 3;
    float4* sorted = wsSorted + (size_t)b * NN;
    float4* ctr = wsCtr + (size_t)b * SS;
    float* o0 = out0 + (size_t)b * 3 * SS;

    __shared__ int cellCnt[512];
    __shared__ int cellBase[512];
    __shared__ unsigned long long red[2][8];

    const int tid = threadIdx.x;
    const int wid = tid >> 6;
    const int lane = tid & 63;

    // --- pass 1: per-Morton-cell counts
    cellCnt[tid] = 0;
    __syncthreads();
    int cellReg[16];
#pragma unroll
    for (int j = 0; j < 16; ++j) {
        int p = tid + j * 512;
        float x = xyz[p * 3 + 0], y = xyz[p * 3 + 1], z = xyz[p * 3 + 2];
        int qx = min(7, (int)(x * 8.0f));
        int qy = min(7, (int)(y * 8.0f));
        int qz = min(7, (int)(z * 8.0f));
        int cell = part3(qx) | (part3(qy) << 1) | (part3(qz) << 2);
        cellReg[j] = cell;
        atomicAdd(&cellCnt[cell], 1);
    }
    __syncthreads();
    int myCnt = cellCnt[tid];
    // inclusive Hillis-Steele scan over 512 cells (thread==cell)
    for (int off = 1; off < 512; off <<= 1) {
        int v = (tid >= off) ? cellCnt[tid - off] : 0;
        __syncthreads();
        cellCnt[tid] += v;
        __syncthreads();
    }
    cellBase[tid] = cellCnt[tid] - myCnt;
    __syncthreads();
    // --- pass 2: scatter to global ws. Slot s stored at (s&15)*512 + (s>>4)
    // so the read-back (thread t owns slots 16t..16t+15) is coalesced.
#pragma unroll
    for (int j = 0; j < 16; ++j) {
        int p = tid + j * 512;
        float x = xyz[p * 3 + 0], y = xyz[p * 3 + 1], z = xyz[p * 3 + 2];
        int pos = atomicAdd(&cellBase[cellReg[j]], 1);
        sorted[(pos & 15) * 512 + (pos >> 4)] = make_float4(x, y, z, __int_as_float(p));
    }
    __threadfence();
    __syncthreads();

    // --- load own 16 Morton-contiguous points into registers, build lane bbox
    float px[16], py[16], pz[16], dist[16];
    int od[16];
    float lox = 1e30f, loy = 1e30f, loz = 1e30f;
    float hix = -1e30f, hiy = -1e30f, hiz = -1e30f;
#pragma unroll
    for (int j = 0; j < 16; ++j) {
        float4 v = sorted[j * 512 + tid];
        px[j] = v.x; py[j] = v.y; pz[j] = v.z;
        od[j] = __float_as_int(v.w);
        dist[j] = 1e10f;
        lox = fminf(lox, v.x); hix = fmaxf(hix, v.x);
        loy = fminf(loy, v.y); hiy = fmaxf(hiy, v.y);
        loz = fminf(loz, v.z); hiz = fmaxf(hiz, v.z);
    }
    // wave bbox via butterfly (one-time)
    float wlox = lox, wloy = loy, wloz = loz, whix = hix, whiy = hiy, whiz = hiz;
#pragma unroll
    for (int off = 1; off < 64; off <<= 1) {
        wlox = fminf(wlox, __shfl_xor(wlox, off));
        wloy = fminf(wloy, __shfl_xor(wloy, off));
        wloz = fminf(wloz, __shfl_xor(wloz, off));
        whix = fmaxf(whix, __shfl_xor(whix, off));
        whiy = fmaxf(whiy, __shfl_xor(whiy, off));
        whiz = fmaxf(whiz, __shfl_xor(whiz, off));
    }

    float cx = xyz[0], cy = xyz[1], cz = xyz[2];
    if (tid == 0) {
        o0[0] = cx; o0[SS] = cy; o0[2 * SS] = cz;
        ctr[0] = make_float4(cx, cy, cz, 0.0f);
    }

    unsigned long long waveKey =
        ((unsigned long long)__float_as_uint(1e10f) << 32) | 0xFFFFFFFFull;
    float wave_bv = 1e10f;  // max dist over this wave's 1024 points (cached)

    for (int s = 1; s < SS; ++s) {
        // wave-level exact prune: if lb >= wave max dist, no dist in the wave
        // can change (min(dist,d)=dist for all) -> candidate & dists stay valid
        float ddx = fmaxf(fmaxf(wlox - cx, cx - whix), 0.0f);
        float ddy = fmaxf(fmaxf(wloy - cy, cy - whiy), 0.0f);
        float ddz = fmaxf(fmaxf(wloz - cz, cz - whiz), 0.0f);
        float lb2 = ddx * ddx + ddy * ddy + ddz * ddz;
        if (__any(lb2 * 0.999f < wave_bv)) {
            float nbv = -1.0f;
            int nbi = 0x7fffffff;
#pragma unroll
            for (int j = 0; j < 16; ++j) {
                float d = sqdist_exact(px[j], py[j], pz[j], cx, cy, cz);
                float nd = fminf(dist[j], d);
                dist[j] = nd;
                bool better = (nd > nbv) || (nd == nbv && od[j] < nbi);
                nbv = better ? nd : nbv;
                nbi = better ? od[j] : nbi;
            }
            // pack (val, min-index tie-break) into one monotone u64 key
            unsigned long long key =
                ((unsigned long long)__float_as_uint(nbv) << 32) | (unsigned)(~nbi);
#pragma unroll
            for (int off = 1; off < 64; off <<= 1) {
                unsigned long long o = __shfl_xor(key, off);
                key = (o > key) ? o : key;
            }
            waveKey = key;
            wave_bv = __uint_as_float((unsigned)(waveKey >> 32));
        }
        if (lane == 0) red[s & 1][wid] = waveKey;
        __syncthreads();
        unsigned long long best = red[s & 1][0];
#pragma unroll
        for (int k = 1; k < 8; ++k) {
            unsigned long long o = red[s & 1][k];
            best = (o > best) ? o : best;
        }
        int wi = (int)(~(unsigned)best);
        cx = xyz[wi * 3 + 0];  // broadcast load, L1/L2-hit
        cy = xyz[wi * 3 + 1];
        cz = xyz[wi * 3 + 2];
        if (tid == 0) {
            o0[s] = cx; o0[SS + s] = cy; o0[2 * SS + s] = cz;
            ctr[s] = make_float4(cx, cy, cz, 0.0f);
        }
    }
}

// ---------------------------------------------------------------------------
// Fused ball-query + MLP + maxpool. Block = 128 threads (2 waves), 2 centers.
// ---------------------------------------------------------------------------
__global__ __launch_bounds__(128) void bqmlp_kernel(const float* __restrict__ xyz_all,
                                                    const float4* __restrict__ wsCtr,
                                                    const float* __restrict__ w1T,
                                                    const float* __restrict__ b1,
                                                    const float* __restrict__ w2T,
                                                    const float* __restrict__ b2,
                                                    const float* __restrict__ w3T,
                                                    const float* __restrict__ b3,
                                                    float* __restrict__ out1) {
    const int b = blockIdx.x >> 10;            // 1024 blocks per batch
    const int s0 = (blockIdx.x & 1023) * 2;    // 2 centers per block
    const float* xyz = xyz_all + (size_t)b * NN * 3;

    __shared__ float relF[2 * KNB * 3];  // [64 rows][3]
    __shared__ float h1T[64 * 64];       // [ch][row]
    __shared__ float h2T[64 * 64];       // [ch][row]

    const int tid = threadIdx.x;
    const int cb = __builtin_amdgcn_readfirstlane(tid >> 6);  // wave id (uniform)
    const int l = tid & 63;

    // ---- ball query: wave cb handles center s0+cb
    {
        float4 cc = wsCtr[(size_t)b * SS + s0 + cb];
        float ccx = cc.x, ccy = cc.y, ccz = cc.z;
        const float R2 = (float)(0.2 * 0.2);
        int total = 0;
        float fx = 0.f, fy = 0.f, fz = 0.f;
        bool have = false;
        for (int chunk = 0; chunk < 128 && total < KNB; ++chunk) {
            int p = chunk * 64 + l;
            float x = xyz[p * 3 + 0], y = xyz[p * 3 + 1], z = xyz[p * 3 + 2];
            float d = sqdist_exact(ccx, ccy, ccz, x, y, z);
            bool hit = (d <= R2);
            unsigned long long mask = __ballot(hit);
            int cnt = __popcll(mask);
            if (cnt) {
                int pos = total + __popcll(mask & ((1ull << l) - 1ull));
                float rx = x - ccx, ry = y - ccy, rz = z - ccz;  // single subs: exact
                if (hit && pos < KNB) {
                    relF[(cb * KNB + pos) * 3 + 0] = rx;
                    relF[(cb * KNB + pos) * 3 + 1] = ry;
                    relF[(cb * KNB + pos) * 3 + 2] = rz;
                }
                if (hit && pos == 0) { fx = rx; fy = ry; fz = rz; have = true; }
                total += cnt;
            }
        }
        unsigned long long hm = __ballot(have);
        if (total < KNB) {
            int src = __ffsll((long long)hm) - 1;
            float gx = __shfl(fx, src), gy = __shfl(fy, src), gz = __shfl(fz, src);
            if (l >= total && l < KNB) {
                relF[(cb * KNB + l) * 3 + 0] = gx;
                relF[(cb * KNB + l) * 3 + 1] = gy;
                relF[(cb * KNB + l) * 3 + 2] = gz;
            }
        }
    }
    __syncthreads();

    const int r = l;  // row 0..63: rows 0..31 center s0, rows 32..63 center s0+1

    // ---- layer 1: rel(3) -> 64, thread covers ch block cb*32..+31 for row r
    {
        float rx = relF[r * 3 + 0], ry = relF[r * 3 + 1], rz = relF[r * 3 + 2];
#pragma unroll
        for (int i = 0; i < 32; ++i) {
            int ch = cb * 32 + i;
            float h = b1[ch];
            h = fmaf(rx, w1T[0 * 64 + ch], h);
            h = fmaf(ry, w1T[1 * 64 + ch], h);
            h = fmaf(rz, w1T[2 * 64 + ch], h);
            h1T[ch * 64 + r] = fmaxf(h, 0.0f);
        }
    }
    __syncthreads();

    // ---- layer 2: 64 -> 64
    {
        float acc[32];
#pragma unroll
        for (int i = 0; i < 32; ++i) acc[i] = b2[cb * 32 + i];
#pragma unroll 4
        for (int j = 0; j < 64; ++j) {
            float a = h1T[j * 64 + r];
            const float* wrow = w2T + j * 64 + cb * 32;
#pragma unroll
            for (int i = 0; i < 32; ++i) acc[i] = fmaf(a, wrow[i], acc[i]);
        }
#pragma unroll
        for (int i = 0; i < 32; ++i) h2T[(cb * 32 + i) * 64 + r] = fmaxf(acc[i], 0.0f);
    }
    __syncthreads();

    // ---- layer 3: 64 -> 128, fused relu + maxpool over the 32 rows/center
    {
        float acc[64];
#pragma unroll
        for (int i = 0; i < 64; ++i) acc[i] = b3[cb * 64 + i];
#pragma unroll 2
        for (int j = 0; j < 64; ++j) {
            float a = h2T[j * 64 + r];
            const float* wrow = w3T + j * 128 + cb * 64;
#pragma unroll
            for (int i = 0; i < 64; ++i) acc[i] = fmaf(a, wrow[i], acc[i]);
        }
#pragma unroll
        for (int i = 0; i < 64; ++i) {
            float v = fmaxf(acc[i], 0.0f);
            v = fmaxf(v, __shfl_xor(v, 1));
            v = fmaxf(v, __shfl_xor(v, 2));
            v = fmaxf(v, __shfl_xor(v, 4));
            v = fmaxf(v, __shfl_xor(v, 8));
            v = fmaxf(v, __shfl_xor(v, 16));
            acc[i] = v;
        }
        if ((l & 31) == 0) {
            int sA = s0 + (l >> 5);
            float* op = out1 + ((size_t)b * 128 + cb * 64) * SS + sA;
#pragma unroll
            for (int i = 0; i < 64; ++i) op[(size_t)i * SS] = acc[i];
        }
    }
}

extern "C" void kernel_launch(void* const* d_in, const int* in_sizes, int n_in,
                              void* d_out, int out_size, void* d_ws, size_t ws_size,
                              hipStream_t stream) {
    (void)in_sizes; (void)n_in; (void)out_size; (void)ws_size;
    const float* xyz = (const float*)d_in[0];
    // d_in[1] = features : unused by the reference
    const float* w1 = (const float*)d_in[2];
    const float* b1 = (const float*)d_in[3];
    const float* w2 = (const float*)d_in[4];
    const float* b2 = (const float*)d_in[5];
    const float* w3 = (const float*)d_in[6];
    const float* b3 = (const float*)d_in[7];
    float* out = (float*)d_out;

    // workspace layout
    float4* wsCtr = (float4*)d_ws;              // B*S float4      (256 KB)
    float4* wsSorted = wsCtr + BB * SS;         // B*N float4      (1 MB)
    float* w1T = (float*)(wsSorted + BB * NN);  // 192 f
    float* w2T = w1T + 192;                     // 4096 f
    float* w3T = w2T + 4096;                    // 8192 f

    prep_kernel<<<1, 256, 0, stream>>>(w1, w2, w3, w1T, w2T, w3T);
    fps_kernel<<<BB, 512, 0, stream>>>(xyz, wsSorted, wsCtr, out);
    bqmlp_kernel<<<BB * (SS / 2), 128, 0, stream>>>(xyz, wsCtr, w1T, b1, w2T, b2,
                                                    w3T, b3, out + BB * 3 * SS);
}

// Round 3
// 2325.894 us; speedup vs baseline: 2.2241x; 1.7041x over previous
//
#include <hip/hip_runtime.h>
#include <cstdint>
#include <cstddef>

#define BB 8
#define NN 8192
#define SS 2048
#define KNB 32

// Bit-exact squared distance matching numpy: (a-b) per component, squares,
// left-to-right sum, no FMA contraction.
__device__ __forceinline__ float sqdist_exact(float ax, float ay, float az,
                                              float bx, float by, float bz) {
#pragma clang fp contract(off)
    float dx = ax - bx;
    float dy = ay - by;
    float dz = az - bz;
    return (dx * dx + dy * dy) + dz * dz;
}

// DPP wave-64 reduce steps (gfx9 lineage: row_shr + row_bcast legal on CDNA4).
// old = identity, bound_ctrl=false -> invalid lanes contribute identity.
template <int CTRL>
__device__ __forceinline__ float dpp_fmax_step(float x) {
    int t = __builtin_amdgcn_update_dpp(__float_as_int(-1.0f), __float_as_int(x),
                                        CTRL, 0xf, 0xf, false);
    return fmaxf(x, __int_as_float(t));
}
template <int CTRL>
__device__ __forceinline__ int dpp_imin_step(int x) {
    int t = __builtin_amdgcn_update_dpp(0x7fffffff, x, CTRL, 0xf, 0xf, false);
    return min(x, t);
}
#define ROW_SHR1 0x111
#define ROW_SHR2 0x112
#define ROW_SHR4 0x114
#define ROW_SHR8 0x118
#define ROW_BC15 0x142
#define ROW_BC31 0x143

// ---------------------------------------------------------------------------
// Weight transpose prep: w1T[c][64], w2T[j][64], w3T[j][128]
// ---------------------------------------------------------------------------
__global__ void prep_kernel(const float* __restrict__ w1, const float* __restrict__ w2,
                            const float* __restrict__ w3, float* __restrict__ w1T,
                            float* __restrict__ w2T, float* __restrict__ w3T) {
    for (int i = threadIdx.x; i < 192; i += 256) {
        int oc = i / 3, c = i % 3;
        w1T[c * 64 + oc] = w1[i];
    }
    for (int i = threadIdx.x; i < 4096; i += 256) {
        int oc = i >> 6, j = i & 63;
        w2T[j * 64 + oc] = w2[i];
    }
    for (int i = threadIdx.x; i < 8192; i += 256) {
        int oc = i >> 6, j = i & 63;
        w3T[j * 128 + oc] = w3[i];
    }
}

// spread 3-bit value to bit positions 0,3,6
__device__ __forceinline__ int part3(int v) {
    return (v & 1) | ((v & 2) << 2) | ((v & 4) << 4);
}

#define PT_LIST(X) X(0) X(1) X(2) X(3) X(4) X(5) X(6) X(7)

// ---------------------------------------------------------------------------
// FPS: one block per batch, 1024 threads (16 waves), 8 points/thread held in
// MACRO-SCALARIZED named registers (no arrays -> nothing can spill to
// scratch). Points counting-sorted by 8x8x8 Morton cell so each wave owns a
// compact half-octant -> wave-uniform exact bbox prune (skips only when
// provably no dist changes; 0.999 margin covers fp rounding). Wave argmax via
// DPP (VALU-speed) value-max + equality index resolve + DPP index-min, ==
// jnp.argmax (max value, first orig index). Cross-wave via parity
// double-buffered LDS keys, ONE barrier/iter; winner coords via
// readfirstlane + scalar broadcast load.
// ---------------------------------------------------------------------------
__global__ __launch_bounds__(1024, 4) void fps_kernel(const float* __restrict__ xyz_all,
                                                      float4* __restrict__ wsSorted,
                                                      float4* __restrict__ wsCtr,
                                                      float* __restrict__ out0) {
    const int b = blockIdx.x;
    const float* xyz = xyz_all + (size_t)b * NN * 3;
    float4* sorted = wsSorted + (size_t)b * NN;
    float4* ctr = wsCtr + (size_t)b * SS;
    float* o0 = out0 + (size_t)b * 3 * SS;

    __shared__ int cellCnt[512];
    __shared__ int cellBase[512];
    __shared__ unsigned long long red[2][16];

    const int tid = threadIdx.x;
    const int wid = tid >> 6;
    const int lane = tid & 63;

    // --- pass 1: per-Morton-cell counts (8 pts/thread)
    if (tid < 512) cellCnt[tid] = 0;
    __syncthreads();
    int cellReg[8];
#pragma unroll
    for (int j = 0; j < 8; ++j) {
        int p = tid + j * 1024;
        float x = xyz[p * 3 + 0], y = xyz[p * 3 + 1], z = xyz[p * 3 + 2];
        int qx = min(7, (int)(x * 8.0f));
        int qy = min(7, (int)(y * 8.0f));
        int qz = min(7, (int)(z * 8.0f));
        cellReg[j] = part3(qx) | (part3(qy) << 1) | (part3(qz) << 2);
        atomicAdd(&cellCnt[cellReg[j]], 1);
    }
    __syncthreads();
    int myCnt = (tid < 512) ? cellCnt[tid] : 0;
    // inclusive Hillis-Steele scan over 512 cells (thread==cell), barriers uniform
    for (int off = 1; off < 512; off <<= 1) {
        int v = 0;
        if (tid < 512 && tid >= off) v = cellCnt[tid - off];
        __syncthreads();
        if (tid < 512) cellCnt[tid] += v;
        __syncthreads();
    }
    if (tid < 512) cellBase[tid] = cellCnt[tid] - myCnt;
    __syncthreads();
    // --- pass 2: scatter to global ws. Slot s stored at (s&7)*1024 + (s>>3)
    // so read-back (thread t owns Morton slots 8t..8t+7) is coalesced.
#pragma unroll
    for (int j = 0; j < 8; ++j) {
        int p = tid + j * 1024;
        float x = xyz[p * 3 + 0], y = xyz[p * 3 + 1], z = xyz[p * 3 + 2];
        int pos = atomicAdd(&cellBase[cellReg[j]], 1);
        sorted[(pos & 7) * 1024 + (pos >> 3)] = make_float4(x, y, z, __int_as_float(p));
    }
    __threadfence();
    __syncthreads();

    // --- load own 8 Morton-contiguous points into named registers + lane bbox
    float lox = 1e30f, loy = 1e30f, loz = 1e30f;
    float hix = -1e30f, hiy = -1e30f, hiz = -1e30f;
#define DECL_PT(i)                          \
    float px##i, py##i, pz##i, dist##i;     \
    int od##i;                              \
    {                                       \
        float4 v = sorted[i * 1024 + tid];  \
        px##i = v.x; py##i = v.y; pz##i = v.z; \
        od##i = __float_as_int(v.w);        \
        dist##i = 1e10f;                    \
        lox = fminf(lox, v.x); hix = fmaxf(hix, v.x); \
        loy = fminf(loy, v.y); hiy = fmaxf(hiy, v.y); \
        loz = fminf(loz, v.z); hiz = fmaxf(hiz, v.z); \
    }
    PT_LIST(DECL_PT)

    // wave bbox via one-time shfl butterfly
    float wlox = lox, wloy = loy, wloz = loz, whix = hix, whiy = hiy, whiz = hiz;
#pragma unroll
    for (int off = 1; off < 64; off <<= 1) {
        wlox = fminf(wlox, __shfl_xor(wlox, off));
        wloy = fminf(wloy, __shfl_xor(wloy, off));
        wloz = fminf(wloz, __shfl_xor(wloz, off));
        whix = fmaxf(whix, __shfl_xor(whix, off));
        whiy = fmaxf(whiy, __shfl_xor(whiy, off));
        whiz = fmaxf(whiz, __shfl_xor(whiz, off));
    }

    float cx = xyz[0], cy = xyz[1], cz = xyz[2];
    if (tid == 0) {
        o0[0] = cx; o0[SS] = cy; o0[2 * SS] = cz;
        ctr[0] = make_float4(cx, cy, cz, 0.0f);
    }

    unsigned long long waveKey =
        ((unsigned long long)__float_as_uint(1e10f) << 32) | 0xFFFFFFFFull;
    float wave_bv = 1e10f;  // max min-dist over this wave's 512 points (cached)

    for (int s = 1; s < SS; ++s) {
        // wave-uniform exact prune: if lb >= wave max dist, no dist can change
        float ddx = fmaxf(fmaxf(wlox - cx, cx - whix), 0.0f);
        float ddy = fmaxf(fmaxf(wloy - cy, cy - whiy), 0.0f);
        float ddz = fmaxf(fmaxf(wloz - cz, cz - whiz), 0.0f);
        float lb2 = ddx * ddx + ddy * ddy + ddz * ddz;
        if (lb2 * 0.999f < wave_bv) {
            float nbv = -1.0f;
#define UPD_PT(i)                                                        \
    {                                                                    \
        float d = sqdist_exact(px##i, py##i, pz##i, cx, cy, cz);         \
        dist##i = fminf(dist##i, d);                                     \
        nbv = fmaxf(nbv, dist##i);                                       \
    }
            PT_LIST(UPD_PT)
            // wave max value via DPP (VALU-speed), result in lane 63
            float m = nbv;
            m = dpp_fmax_step<ROW_SHR1>(m);
            m = dpp_fmax_step<ROW_SHR2>(m);
            m = dpp_fmax_step<ROW_SHR4>(m);
            m = dpp_fmax_step<ROW_SHR8>(m);
            m = dpp_fmax_step<ROW_BC15>(m);
            m = dpp_fmax_step<ROW_BC31>(m);
            float wv = __int_as_float(__builtin_amdgcn_readlane(__float_as_int(m), 63));
            // first-orig-index among exact max holders
            int cand = 0x7fffffff;
#define IDX_PT(i) cand = (dist##i == wv) ? min(cand, od##i) : cand;
            PT_LIST(IDX_PT)
            cand = dpp_imin_step<ROW_SHR1>(cand);
            cand = dpp_imin_step<ROW_SHR2>(cand);
            cand = dpp_imin_step<ROW_SHR4>(cand);
            cand = dpp_imin_step<ROW_SHR8>(cand);
            cand = dpp_imin_step<ROW_BC15>(cand);
            cand = dpp_imin_step<ROW_BC31>(cand);
            int wiw = __builtin_amdgcn_readlane(cand, 63);
            waveKey = ((unsigned long long)__float_as_uint(wv) << 32) |
                      (unsigned)(~(unsigned)wiw);
            wave_bv = wv;
        }
        if (lane == 0) red[s & 1][wid] = waveKey;
        __syncthreads();
        unsigned long long best = red[s & 1][0];
#pragma unroll
        for (int k = 1; k < 16; ++k) {
            unsigned long long o = red[s & 1][k];
            best = (o > best) ? o : best;
        }
        int wi = (int)(~(unsigned)best);
        int wiu = __builtin_amdgcn_readfirstlane(wi);
        cx = xyz[wiu * 3 + 0];  // scalar broadcast load (s_load)
        cy = xyz[wiu * 3 + 1];
        cz = xyz[wiu * 3 + 2];
        if (tid == 0) {
            o0[s] = cx; o0[SS + s] = cy; o0[2 * SS + s] = cz;
            ctr[s] = make_float4(cx, cy, cz, 0.0f);
        }
    }
}

// ---------------------------------------------------------------------------
// Fused ball-query + MLP + maxpool. Block = 128 threads (2 waves), 2 centers.
// ---------------------------------------------------------------------------
__global__ __launch_bounds__(128) void bqmlp_kernel(const float* __restrict__ xyz_all,
                                                    const float4* __restrict__ wsCtr,
                                                    const float* __restrict__ w1T,
                                                    const float* __restrict__ b1,
                                                    const float* __restrict__ w2T,
                                                    const float* __restrict__ b2,
                                                    const float* __restrict__ w3T,
                                                    const float* __restrict__ b3,
                                                    float* __restrict__ out1) {
    const int b = blockIdx.x >> 10;            // 1024 blocks per batch
    const int s0 = (blockIdx.x & 1023) * 2;    // 2 centers per block
    const float* xyz = xyz_all + (size_t)b * NN * 3;

    __shared__ float relF[2 * KNB * 3];  // [64 rows][3]
    __shared__ float h1T[64 * 64];       // [ch][row]
    __shared__ float h2T[64 * 64];       // [ch][row]

    const int tid = threadIdx.x;
    const int cb = __builtin_amdgcn_readfirstlane(tid >> 6);  // wave id (uniform)
    const int l = tid & 63;

    // ---- ball query: wave cb handles center s0+cb
    {
        float4 cc = wsCtr[(size_t)b * SS + s0 + cb];
        float ccx = cc.x, ccy = cc.y, ccz = cc.z;
        const float R2 = (float)(0.2 * 0.2);
        int total = 0;
        float fx = 0.f, fy = 0.f, fz = 0.f;
        bool have = false;
        for (int chunk = 0; chunk < 128 && total < KNB; ++chunk) {
            int p = chunk * 64 + l;
            float x = xyz[p * 3 + 0], y = xyz[p * 3 + 1], z = xyz[p * 3 + 2];
            float d = sqdist_exact(ccx, ccy, ccz, x, y, z);
            bool hit = (d <= R2);
            unsigned long long mask = __ballot(hit);
            int cnt = __popcll(mask);
            if (cnt) {
                int pos = total + __popcll(mask & ((1ull << l) - 1ull));
                float rx = x - ccx, ry = y - ccy, rz = z - ccz;  // single subs: exact
                if (hit && pos < KNB) {
                    relF[(cb * KNB + pos) * 3 + 0] = rx;
                    relF[(cb * KNB + pos) * 3 + 1] = ry;
                    relF[(cb * KNB + pos) * 3 + 2] = rz;
                }
                if (hit && pos == 0) { fx = rx; fy = ry; fz = rz; have = true; }
                total += cnt;
            }
        }
        unsigned long long hm = __ballot(have);
        if (total < KNB) {
            int src = __ffsll((long long)hm) - 1;
            float gx = __shfl(fx, src), gy = __shfl(fy, src), gz = __shfl(fz, src);
            if (l >= total && l < KNB) {
                relF[(cb * KNB + l) * 3 + 0] = gx;
                relF[(cb * KNB + l) * 3 + 1] = gy;
                relF[(cb * KNB + l) * 3 + 2] = gz;
            }
        }
    }
    __syncthreads();

    const int r = l;  // row 0..63: rows 0..31 center s0, rows 32..63 center s0+1

    // ---- layer 1: rel(3) -> 64, thread covers ch block cb*32..+31 for row r
    {
        float rx = relF[r * 3 + 0], ry = relF[r * 3 + 1], rz = relF[r * 3 + 2];
#pragma unroll
        for (int i = 0; i < 32; ++i) {
            int ch = cb * 32 + i;
            float h = b1[ch];
            h = fmaf(rx, w1T[0 * 64 + ch], h);
            h = fmaf(ry, w1T[1 * 64 + ch], h);
            h = fmaf(rz, w1T[2 * 64 + ch], h);
            h1T[ch * 64 + r] = fmaxf(h, 0.0f);
        }
    }
    __syncthreads();

    // ---- layer 2: 64 -> 64
    {
        float acc[32];
#pragma unroll
        for (int i = 0; i < 32; ++i) acc[i] = b2[cb * 32 + i];
#pragma unroll 4
        for (int j = 0; j < 64; ++j) {
            float a = h1T[j * 64 + r];
            const float* wrow = w2T + j * 64 + cb * 32;
#pragma unroll
            for (int i = 0; i < 32; ++i) acc[i] = fmaf(a, wrow[i], acc[i]);
        }
#pragma unroll
        for (int i = 0; i < 32; ++i) h2T[(cb * 32 + i) * 64 + r] = fmaxf(acc[i], 0.0f);
    }
    __syncthreads();

    // ---- layer 3: 64 -> 128, fused relu + maxpool over the 32 rows/center
    {
        float acc[64];
#pragma unroll
        for (int i = 0; i < 64; ++i) acc[i] = b3[cb * 64 + i];
#pragma unroll 2
        for (int j = 0; j < 64; ++j) {
            float a = h2T[j * 64 + r];
            const float* wrow = w3T + j * 128 + cb * 64;
#pragma unroll
            for (int i = 0; i < 64; ++i) acc[i] = fmaf(a, wrow[i], acc[i]);
        }
#pragma unroll
        for (int i = 0; i < 64; ++i) {
            float v = fmaxf(acc[i], 0.0f);
            v = fmaxf(v, __shfl_xor(v, 1));
            v = fmaxf(v, __shfl_xor(v, 2));
            v = fmaxf(v, __shfl_xor(v, 4));
            v = fmaxf(v, __shfl_xor(v, 8));
            v = fmaxf(v, __shfl_xor(v, 16));
            acc[i] = v;
        }
        if ((l & 31) == 0) {
            int sA = s0 + (l >> 5);
            float* op = out1 + ((size_t)b * 128 + cb * 64) * SS + sA;
#pragma unroll
            for (int i = 0; i < 64; ++i) op[(size_t)i * SS] = acc[i];
        }
    }
}

extern "C" void kernel_launch(void* const* d_in, const int* in_sizes, int n_in,
                              void* d_out, int out_size, void* d_ws, size_t ws_size,
                              hipStream_t stream) {
    (void)in_sizes; (void)n_in; (void)out_size; (void)ws_size;
    const float* xyz = (const float*)d_in[0];
    // d_in[1] = features : unused by the reference
    const float* w1 = (const float*)d_in[2];
    const float* b1 = (const float*)d_in[3];
    const float* w2 = (const float*)d_in[4];
    const float* b2 = (const float*)d_in[5];
    const float* w3 = (const float*)d_in[6];
    const float* b3 = (const float*)d_in[7];
    float* out = (float*)d_out;

    // workspace layout
    float4* wsCtr = (float4*)d_ws;              // B*S float4      (256 KB)
    float4* wsSorted = wsCtr + BB * SS;         // B*N float4      (1 MB)
    float* w1T = (float*)(wsSorted + BB * NN);  // 192 f
    float* w2T = w1T + 192;                     // 4096 f
    float* w3T = w2T + 4096;                    // 8192 f

    prep_kernel<<<1, 256, 0, stream>>>(w1, w2, w3, w1T, w2T, w3T);
    fps_kernel<<<BB, 1024, 0, stream>>>(xyz, wsSorted, wsCtr, out);
    bqmlp_kernel<<<BB * (SS / 2), 128, 0, stream>>>(xyz, wsCtr, w1T, b1, w2T, b2,
                                                    w3T, b3, out + BB * 3 * SS);
}